// Round 1
// baseline (487.212 us; speedup 1.0000x reference)
//
#include <hip/hip_runtime.h>

// Geometry: M=N=128, padded S=256. Two volumes (b*d=2).
// A,B scratch: [v][z<128][y:256][x:256] complex fp32 = 128 MiB each.
static constexpr size_t VS   = 8388608;  // 128*256*256 complex per volume
static constexpr int    ZSTR = 65536;    // 256*256
static constexpr int    YSTR = 256;
static constexpr int    LPAD = 514;      // LDS line stride (2*257) breaks bank conflicts

__device__ __forceinline__ float2 cmulf(float2 a, float2 b){
    return make_float2(a.x*b.x - a.y*b.y, a.x*b.y + a.y*b.x);
}

__device__ __forceinline__ void init_tw(float2* tw){
    int k = threadIdx.x;
    if (k < 128){
        float s, c;
        sincosf(-0.024543692606170259f * (float)k, &s, &c); // -2*pi/256 * k
        tw[k] = make_float2(c, s);
    }
}

// Stockham radix-2 256-pt FFT in LDS. Input in b0 (natural order), result in b0
// (natural order). TPL = threads per line, t in [0,TPL). DIR=+1 fwd, -1 inv (unscaled).
template<int DIR, int TPL>
__device__ __forceinline__ void fft256(float2* b0, float2* b1, const float2* tw, int t){
    float2* src = b0; float2* dst = b1;
#pragma unroll
    for (int i = 0; i < 8; ++i){
        const int s = 1 << i;
        __syncthreads();
#pragma unroll
        for (int j0 = 0; j0 < 128; j0 += TPL){
            int j = j0 + t;
            int q = j & (s - 1);
            float2 a = src[j];
            float2 b = src[j + 128];
            float2 w = tw[j - q];            // tw index = p<<i = j-q
            if (DIR < 0) w.y = -w.y;         // conj for inverse
            float2 sm = make_float2(a.x + b.x, a.y + b.y);
            float2 df = make_float2(a.x - b.x, a.y - b.y);
            int o = 2*j - q;
            dst[o]     = sm;
            dst[o + s] = cmulf(df, w);
        }
        float2* tmp = src; src = dst; dst = tmp;
    }
    __syncthreads();
}

// ---- contiguous-axis kernels (x): 2 lines per 256-thread block ----

// P1: read input, val = sqrt(relu(f*gz^2)), zero-pad 128->256, forward FFT along x.
// Writes A[v][z<128][y<128][0..256).
__global__ void __launch_bounds__(256) k_p1(const float* __restrict__ in, float2* __restrict__ A){
    __shared__ float2 tw[128];
    __shared__ float2 buf[2][2][256];
    init_tw(tw);
    int tid = threadIdx.x;
    int line = tid >> 7, t = tid & 127;
    int bid = blockIdx.x;                  // v*8192 + z*64 + ypair
    int ypair = bid & 63;
    int z = (bid >> 6) & 127;
    int v = bid >> 13;
    int y = ypair*2 + line;
    float g = z * (1.0f/127.0f);
    float g2 = g*g;
    float val = in[(((size_t)(v*128 + z))*128 + y)*128 + t] * g2;
    buf[line][0][t]     = make_float2(val > 0.f ? sqrtf(val) : 0.f, 0.f);
    buf[line][0][t+128] = make_float2(0.f, 0.f);
    fft256<1,128>(buf[line][0], buf[line][1], tw, t);
    float2* dst = A + (size_t)v*VS + (size_t)z*ZSTR + (size_t)y*YSTR;
    dst[t]     = buf[line][0][t];
    dst[t+128] = buf[line][0][t+128];
}

// P5: inverse FFT along x, in-place on B, all 256 points.
__global__ void __launch_bounds__(256) k_p5(float2* __restrict__ B){
    __shared__ float2 tw[128];
    __shared__ float2 buf[2][2][256];
    init_tw(tw);
    int tid = threadIdx.x;
    int line = tid >> 7, t = tid & 127;
    int bid = blockIdx.x;                  // v*16384 + zn*128 + ypair
    int ypair = bid & 127;
    int zn = (bid >> 7) & 127;
    int v = bid >> 14;
    int y = ypair*2 + line;
    float2* p = B + (size_t)v*VS + (size_t)zn*ZSTR + (size_t)y*YSTR;
    buf[line][0][t]     = p[t];
    buf[line][0][t+128] = p[t+128];
    fft256<-1,128>(buf[line][0], buf[line][1], tw, t);
    p[t]     = buf[line][0][t];
    p[t+128] = buf[line][0][t+128];
}

// ---- strided-axis kernels: 8 adjacent-x lines per 256-thread block ----

__device__ __forceinline__ float2* SB0(float2* sh, int l){ return sh + l*LPAD; }
__device__ __forceinline__ float2* SB1(float2* sh, int l){ return sh + l*LPAD + 257; }

template<int DIR, int NIN>
__device__ __forceinline__ void fft8_load_run(float2* sh, float2* tw,
                                              const float2* __restrict__ gbase, size_t stride){
    init_tw(tw);
    for (int idx = threadIdx.x; idx < 2048; idx += 256){
        int l = idx & 7, k = idx >> 3;
        float2 val = (k < NIN) ? gbase[(size_t)k*stride + l] : make_float2(0.f, 0.f);
        SB0(sh, l)[k] = val;
    }
    int l = threadIdx.x >> 5, t = threadIdx.x & 31;
    fft256<DIR,32>(SB0(sh, l), SB1(sh, l), tw, t);
}

// P2: forward FFT along y for z<128, all x. Read y<128, write all 256. In-place.
__global__ void __launch_bounds__(256) k_p2(float2* __restrict__ A){
    __shared__ float2 tw[128];
    __shared__ float2 sh[8*LPAD];
    int bid = blockIdx.x;                  // v*4096 + z*32 + xblk
    int xblk = bid & 31;
    int z = (bid >> 5) & 127;
    int v = bid >> 12;
    float2* gbase = A + (size_t)v*VS + (size_t)z*ZSTR + xblk*8;
    fft8_load_run<1,128>(sh, tw, gbase, YSTR);
    for (int idx = threadIdx.x; idx < 2048; idx += 256){
        int l = idx & 7, k = idx >> 3;
        gbase[(size_t)k*YSTR + l] = SB0(sh, l)[k];
    }
}

// P3: forward FFT along z for all (y,x). Read z<128, STORE ONLY z<128 (resample
// never reads natural z>=128). In-place.
__global__ void __launch_bounds__(256) k_p3(float2* __restrict__ A){
    __shared__ float2 tw[128];
    __shared__ float2 sh[8*LPAD];
    int bid = blockIdx.x;                  // v*8192 + y*32 + xblk
    int xblk = bid & 31;
    int y = (bid >> 5) & 255;
    int v = bid >> 13;
    float2* gbase = A + (size_t)v*VS + (size_t)y*YSTR + xblk*8;
    fft8_load_run<1,128>(sh, tw, gbase, ZSTR);
    for (int idx = threadIdx.x; idx < 1024; idx += 256){
        int l = idx & 7, k = idx >> 3;
        gbase[(size_t)k*ZSTR + l] = SB0(sh, l)[k];
    }
}

// P4: Stolt resample + both fftshifts + mask + |gz|/gznew scaling.  A -> B.
// Iterates shifted coords zs=zn+128 (zn in [0,128)), ys, xs; writes natural
// index B[v][zn][(ys+128)&255][(xs+128)&255].
__global__ void __launch_bounds__(256) k_p4(const float2* __restrict__ A, float2* __restrict__ B){
    int xs = threadIdx.x;
    int bid = blockIdx.x;                  // v*32768 + zn*256 + ys
    int ys = bid & 255;
    int zn = (bid >> 8) & 127;
    int v  = bid >> 15;
    int yn = (ys + 128) & 255;
    int xn = (xs + 128) & 255;
    float2* dst = B + (size_t)v*VS + (size_t)zn*ZSTR + (size_t)yn*YSTR + xn;
    if (zn == 0){ *dst = make_float2(0.f, 0.f); return; }   // mask: zs>=129
    float gz = zn * (1.0f/128.0f);
    float gy = (ys - 128) * (1.0f/128.0f);
    float gx = (xs - 128) * (1.0f/128.0f);
    float gznew = sqrtf(0.1024f*(gx*gx + gy*gy) + gz*gz);   // fk = 0.1024
    float pz = (gznew + 1.0f)*128.0f - 0.5f;                // shifted-z coord, >= 128.5
    float z0f = floorf(pz);
    float dz = pz - z0f;
    int z0 = (int)z0f;
    const float2* Av = A + (size_t)v*VS;
    float2 acc = make_float2(0.f, 0.f);
#pragma unroll
    for (int zi = 0; zi < 2; ++zi){
        int zt = z0 + zi;
        float wz = zi ? dz : (1.0f - dz);
        if (zt >= 128 && zt < 256){
            const float2* pl = Av + (size_t)(zt - 128)*ZSTR;
#pragma unroll
            for (int yi = 0; yi < 2; ++yi){
                int yt = ys - 1 + yi;
                if (yt >= 0){
                    const float2* row = pl + (size_t)((yt + 128) & 255)*YSTR;
#pragma unroll
                    for (int xi = 0; xi < 2; ++xi){
                        int xt = xs - 1 + xi;
                        if (xt >= 0){
                            float2 val = row[(xt + 128) & 255];
                            acc.x += wz*val.x;
                            acc.y += wz*val.y;
                        }
                    }
                }
            }
        }
    }
    float wf = 0.25f * gz / (gznew + 1e-8f);   // 0.25 = wy*wx (both exactly 0.5)
    *dst = make_float2(acc.x*wf, acc.y*wf);
}

// P6: inverse FFT along y for zn<128, x<128 only. Read all 256 y, write y<128. In-place.
__global__ void __launch_bounds__(256) k_p6(float2* __restrict__ B){
    __shared__ float2 tw[128];
    __shared__ float2 sh[8*LPAD];
    int bid = blockIdx.x;                  // v*2048 + zn*16 + xblk
    int xblk = bid & 15;
    int zn = (bid >> 4) & 127;
    int v = bid >> 11;
    float2* gbase = B + (size_t)v*VS + (size_t)zn*ZSTR + xblk*8;
    fft8_load_run<-1,256>(sh, tw, gbase, YSTR);
    for (int idx = threadIdx.x; idx < 1024; idx += 256){
        int l = idx & 7, k = idx >> 3;
        gbase[(size_t)k*YSTR + l] = SB0(sh, l)[k];
    }
}

// P7: inverse FFT along z for y<128, x<128. Read zn<128 (rest structurally zero),
// output real part of z<128 scaled by 1/256^3 into d_out.
__global__ void __launch_bounds__(256) k_p7(const float2* __restrict__ B, float* __restrict__ out){
    __shared__ float2 tw[128];
    __shared__ float2 sh[8*LPAD];
    int bid = blockIdx.x;                  // v*2048 + y*16 + xblk
    int xblk = bid & 15;
    int y = (bid >> 4) & 127;
    int v = bid >> 11;
    const float2* gbase = B + (size_t)v*VS + (size_t)y*YSTR + xblk*8;
    fft8_load_run<-1,128>(sh, tw, gbase, ZSTR);
    const float scale = 1.0f/16777216.0f;  // 1/256^3
    for (int idx = threadIdx.x; idx < 1024; idx += 256){
        int l = idx & 7, k = idx >> 3;     // k = output z, l = x offset
        out[(((size_t)(v*128 + k))*128 + y)*128 + xblk*8 + l] = SB0(sh, l)[k].x * scale;
    }
}

extern "C" void kernel_launch(void* const* d_in, const int* in_sizes, int n_in,
                              void* d_out, int out_size, void* d_ws, size_t ws_size,
                              hipStream_t stream){
    const float* in = (const float*)d_in[0];
    float* out = (float*)d_out;
    float2* A = (float2*)d_ws;             // 2 volumes * 128*256*256 complex = 128 MiB
    float2* B = A + 2*VS;                  // another 128 MiB
    k_p1<<<16384, 256, 0, stream>>>(in, A);
    k_p2<<< 8192, 256, 0, stream>>>(A);
    k_p3<<<16384, 256, 0, stream>>>(A);
    k_p4<<<65536, 256, 0, stream>>>(A, B);
    k_p5<<<32768, 256, 0, stream>>>(B);
    k_p6<<< 4096, 256, 0, stream>>>(B);
    k_p7<<< 4096, 256, 0, stream>>>(B, out);
}

// Round 2
// 354.677 us; speedup vs baseline: 1.3737x; 1.3737x over previous
//
#include <hip/hip_runtime.h>

// Geometry: M=N=128, padded S=256. Two volumes (b*d=2).
// A,B scratch: [v][z<128][y:256][x:256] complex fp32 = 128 MiB each.
static constexpr size_t VS   = 8388608;  // 128*256*256 complex per volume
static constexpr int    ZSTR = 65536;    // 256*256
static constexpr int    YSTR = 256;
static constexpr int    LSTR = 261;      // LDS line stride (float2); 261 mod 16 = 5 spreads bank pairs

__device__ __forceinline__ float2 cmulf(float2 a, float2 b){
    return make_float2(a.x*b.x - a.y*b.y, a.x*b.y + a.y*b.x);
}

constexpr int BREV(int k){ return ((k&1)<<3)|((k&2)<<1)|((k&4)>>1)|((k&8)>>3); }

__device__ __forceinline__ void bf(float2& a, float2& b, float c, float s){
    float tx = a.x - b.x, ty = a.y - b.y;
    a.x += b.x; a.y += b.y;
    b.x = tx*c - ty*s;
    b.y = tx*s + ty*c;
}

// Fully-unrolled 16-pt DIF FFT, natural input, bit-reversed output: X[k] = r[BREV(k)].
// DIR=-1 forward (e^{-i...}), DIR=+1 inverse (unscaled).
template<int DIR>
__device__ __forceinline__ void fft16(float2 r[16]){
    constexpr float D = (float)DIR;
    constexpr float C16[8] = {1.f, 0.92387953f, 0.70710678f, 0.38268343f, 0.f, -0.38268343f, -0.70710678f, -0.92387953f};
    constexpr float S16[8] = {0.f, 0.38268343f, 0.70710678f, 0.92387953f, 1.f, 0.92387953f, 0.70710678f, 0.38268343f};
#pragma unroll
    for (int j = 0; j < 8; ++j) bf(r[j], r[j+8], C16[j], D*S16[j]);
    constexpr float C8[4] = {1.f, 0.70710678f, 0.f, -0.70710678f};
    constexpr float S8[4] = {0.f, 0.70710678f, 1.f, 0.70710678f};
#pragma unroll
    for (int g = 0; g < 16; g += 8)
#pragma unroll
        for (int j = 0; j < 4; ++j) bf(r[g+j], r[g+j+4], C8[j], D*S8[j]);
#pragma unroll
    for (int g = 0; g < 16; g += 4){
        bf(r[g],   r[g+2], 1.f, 0.f);
        bf(r[g+1], r[g+3], 0.f, D);
    }
#pragma unroll
    for (int g = 0; g < 16; g += 2) bf(r[g], r[g+1], 1.f, 0.f);
}

// Middle of four-step 256-pt FFT (256 = 16x16). On entry r[n1] = x[16*n1 + t]
// for this thread's n2=t, line l. On exit r[BREV(k2)] = X[t + 16*k2] (t now = k1).
// Uses swizzled LDS transpose; sh is 16*LSTR float2, shared per block.
template<int DIR>
__device__ __forceinline__ void mid256(float2 r[16], float2* sh, int t, int l){
    fft16<DIR>(r);                                   // y[k1] in r[BREV(k1)]
    float s, c;
    __sincosf((float)DIR * 0.0245436926f * (float)t, &s, &c);  // w1 = e^{DIR*2pi*i*t/256}
    float2 w1 = make_float2(c, s), wc = w1;
#pragma unroll
    for (int k1 = 1; k1 < 16; ++k1){                 // y[k1] *= w1^k1
        float2& v = r[BREV(k1)];
        v = cmulf(v, wc);
        wc = cmulf(wc, w1);
    }
    __syncthreads();
#pragma unroll
    for (int k1 = 0; k1 < 16; ++k1)                  // z[k1][n2=t], swizzled
        sh[l*LSTR + k1*16 + ((t + k1) & 15)] = r[BREV(k1)];
    __syncthreads();
#pragma unroll
    for (int n2 = 0; n2 < 16; ++n2)                  // thread t is now k1
        r[n2] = sh[l*LSTR + t*16 + ((n2 + t) & 15)];
    fft16<DIR>(r);                                   // X[t + 16*k2] in r[BREV(k2)]
}

// Strided-axis FFT: 16 consecutive x per block (128-B segments), stride S elements.
// Reads only z<NIN (rest structurally zero), writes only z<NOUT. Direct global<->reg.
template<int DIR, int NIN, int NOUT>
__device__ __forceinline__ void fft_strided(float2* g, int S){
    __shared__ float2 sh[16*LSTR];
    int t = threadIdx.x >> 4, l = threadIdx.x & 15;
    float2 r[16];
#pragma unroll
    for (int n1 = 0; n1 < 16; ++n1)
        r[n1] = (n1 < NIN/16) ? g[(size_t)(16*n1 + t)*S + l] : make_float2(0.f, 0.f);
    mid256<DIR>(r, sh, t, l);
#pragma unroll
    for (int k2 = 0; k2 < 16; ++k2)
        if (k2 < NOUT/16) g[(size_t)(t + 16*k2)*S + l] = r[BREV(k2)];
}

// P1: read input, val = sqrt(relu(f*gz^2)), zero-pad 128->256, forward FFT along x.
// 16 (z,y) rows per block (y<128). Writes A[v][z][y][0..256).
__global__ void __launch_bounds__(256) k_p1(const float* __restrict__ in, float2* __restrict__ A){
    __shared__ float2 sh[16*LSTR];
    __shared__ float shin[16*130];
    int th = threadIdx.x, bid = blockIdx.x;          // v*1024 + z*8 + yc
    int yc = bid & 7, z = (bid >> 3) & 127, v = bid >> 10;
    float gz = z * (1.0f/127.0f);
    float g2 = gz*gz;
    const float* src = in + (((size_t)(v*128 + z))*128 + yc*16)*128;
    for (int idx = th; idx < 2048; idx += 256){
        float val = src[idx] * g2;
        shin[(idx >> 7)*130 + (idx & 127)] = val > 0.f ? sqrtf(val) : 0.f;
    }
    __syncthreads();
    int t = th >> 4, l = th & 15;
    float2 r[16];
#pragma unroll
    for (int n1 = 0; n1 < 16; ++n1)
        r[n1] = (n1 < 8) ? make_float2(shin[l*130 + 16*n1 + t], 0.f) : make_float2(0.f, 0.f);
    mid256<-1>(r, sh, t, l);
    __syncthreads();
#pragma unroll
    for (int k2 = 0; k2 < 16; ++k2) sh[l*LSTR + t + 16*k2] = r[BREV(k2)];
    __syncthreads();
    float2* dst = A + (size_t)v*VS + (size_t)z*ZSTR + (size_t)(yc*16)*YSTR;  // 16 rows contiguous
    for (int idx = th; idx < 4096; idx += 256)
        dst[idx] = sh[(idx >> 8)*LSTR + (idx & 255)];
}

// P2: forward FFT along y for z<128, all x. Read y<128, write all 256. In-place.
__global__ void __launch_bounds__(256) k_p2(float2* __restrict__ A){
    int bid = blockIdx.x;                            // v*2048 + z*16 + xb
    int xb = bid & 15, z = (bid >> 4) & 127, v = bid >> 11;
    fft_strided<-1,128,256>(A + (size_t)v*VS + (size_t)z*ZSTR + xb*16, YSTR);
}

// P3: forward FFT along z for all (y,x). Read z<128, write only z<128. In-place.
__global__ void __launch_bounds__(256) k_p3(float2* __restrict__ A){
    int bid = blockIdx.x;                            // v*4096 + y*16 + xb
    int xb = bid & 15, y = (bid >> 4) & 255, v = bid >> 12;
    fft_strided<-1,128,128>(A + (size_t)v*VS + (size_t)y*YSTR + xb*16, ZSTR);
}

// P4: Stolt resample + both fftshifts + mask + |gz|/gznew scaling.  A -> B.
__global__ void __launch_bounds__(256) k_p4(const float2* __restrict__ A, float2* __restrict__ B){
    int xs = threadIdx.x;
    int bid = blockIdx.x;                            // v*32768 + zn*256 + ys
    int ys = bid & 255;
    int zn = (bid >> 8) & 127;
    int v  = bid >> 15;
    int yn = (ys + 128) & 255;
    int xn = (xs + 128) & 255;
    float2* dst = B + (size_t)v*VS + (size_t)zn*ZSTR + (size_t)yn*YSTR + xn;
    if (zn == 0){ *dst = make_float2(0.f, 0.f); return; }   // mask: zs>=129
    float gz = zn * (1.0f/128.0f);
    float gy = (ys - 128) * (1.0f/128.0f);
    float gx = (xs - 128) * (1.0f/128.0f);
    float gznew = sqrtf(0.1024f*(gx*gx + gy*gy) + gz*gz);   // fk = 0.1024
    float pz = (gznew + 1.0f)*128.0f - 0.5f;                // shifted-z coord, >= 128.5
    float z0f = floorf(pz);
    float dz = pz - z0f;
    int z0 = (int)z0f;
    const float2* Av = A + (size_t)v*VS;
    float2 acc = make_float2(0.f, 0.f);
#pragma unroll
    for (int zi = 0; zi < 2; ++zi){
        int zt = z0 + zi;
        float wz = zi ? dz : (1.0f - dz);
        if (zt >= 128 && zt < 256){
            const float2* pl = Av + (size_t)(zt - 128)*ZSTR;
#pragma unroll
            for (int yi = 0; yi < 2; ++yi){
                int yt = ys - 1 + yi;
                if (yt >= 0){
                    const float2* row = pl + (size_t)((yt + 128) & 255)*YSTR;
#pragma unroll
                    for (int xi = 0; xi < 2; ++xi){
                        int xt = xs - 1 + xi;
                        if (xt >= 0){
                            float2 val = row[(xt + 128) & 255];
                            acc.x += wz*val.x;
                            acc.y += wz*val.y;
                        }
                    }
                }
            }
        }
    }
    float wf = 0.25f * gz / (gznew + 1e-8f);   // 0.25 = wy*wx (both exactly 0.5)
    *dst = make_float2(acc.x*wf, acc.y*wf);
}

// P5: inverse FFT along x, in-place on B, all 256 points. 16 (zn,y) rows per block.
__global__ void __launch_bounds__(256) k_p5(float2* __restrict__ B){
    __shared__ float2 sh[16*LSTR];
    int th = threadIdx.x, bid = blockIdx.x;          // v*2048 + zn*16 + yc
    int yc = bid & 15, zn = (bid >> 4) & 127, v = bid >> 11;
    float2* base = B + (size_t)v*VS + (size_t)zn*ZSTR + (size_t)(yc*16)*YSTR;  // 16 rows contiguous
    for (int idx = th; idx < 4096; idx += 256)
        sh[(idx >> 8)*LSTR + (idx & 255)] = base[idx];
    __syncthreads();
    int t = th >> 4, l = th & 15;
    float2 r[16];
#pragma unroll
    for (int n1 = 0; n1 < 16; ++n1)
        r[n1] = sh[l*LSTR + 16*n1 + t];
    mid256<1>(r, sh, t, l);
    __syncthreads();
#pragma unroll
    for (int k2 = 0; k2 < 16; ++k2) sh[l*LSTR + t + 16*k2] = r[BREV(k2)];
    __syncthreads();
    for (int idx = th; idx < 4096; idx += 256)
        base[idx] = sh[(idx >> 8)*LSTR + (idx & 255)];
}

// P6: inverse FFT along y for zn<128, x<128 only. Read all 256 y, write y<128. In-place.
__global__ void __launch_bounds__(256) k_p6(float2* __restrict__ B){
    int bid = blockIdx.x;                            // v*1024 + zn*8 + xb
    int xb = bid & 7, zn = (bid >> 3) & 127, v = bid >> 10;
    fft_strided<1,256,128>(B + (size_t)v*VS + (size_t)zn*ZSTR + xb*16, YSTR);
}

// P7: inverse FFT along z for y<128, x<128. Read zn<128 (rest structurally zero),
// output real part of z<128 scaled by 1/256^3 into d_out.
__global__ void __launch_bounds__(256) k_p7(const float2* __restrict__ B, float* __restrict__ out){
    __shared__ float2 sh[16*LSTR];
    int bid = blockIdx.x;                            // v*1024 + y*8 + xb
    int xb = bid & 7, y = (bid >> 3) & 127, v = bid >> 10;
    const float2* g = B + (size_t)v*VS + (size_t)y*YSTR + xb*16;
    int t = threadIdx.x >> 4, l = threadIdx.x & 15;
    float2 r[16];
#pragma unroll
    for (int n1 = 0; n1 < 16; ++n1)
        r[n1] = (n1 < 8) ? g[(size_t)(16*n1 + t)*ZSTR + l] : make_float2(0.f, 0.f);
    mid256<1>(r, sh, t, l);
    const float sc = 1.0f/16777216.0f;               // 1/256^3
    float* dst = out + ((size_t)(v*128)*128 + y)*128 + xb*16 + l;
#pragma unroll
    for (int k2 = 0; k2 < 8; ++k2)                   // k = t + 16*k2 < 128
        dst[(size_t)(t + 16*k2)*16384] = r[BREV(k2)].x * sc;
}

extern "C" void kernel_launch(void* const* d_in, const int* in_sizes, int n_in,
                              void* d_out, int out_size, void* d_ws, size_t ws_size,
                              hipStream_t stream){
    const float* in = (const float*)d_in[0];
    float* out = (float*)d_out;
    float2* A = (float2*)d_ws;             // 2 volumes * 128*256*256 complex = 128 MiB
    float2* B = A + 2*VS;                  // another 128 MiB
    k_p1<<< 2048, 256, 0, stream>>>(in, A);
    k_p2<<< 4096, 256, 0, stream>>>(A);
    k_p3<<< 8192, 256, 0, stream>>>(A);
    k_p4<<<65536, 256, 0, stream>>>(A, B);
    k_p5<<< 4096, 256, 0, stream>>>(B);
    k_p6<<< 2048, 256, 0, stream>>>(B);
    k_p7<<< 2048, 256, 0, stream>>>(B, out);
}

// Round 3
// 313.433 us; speedup vs baseline: 1.5544x; 1.1316x over previous
//
#include <hip/hip_runtime.h>

// Geometry: M=N=128, padded S=256. Two volumes (b*d=2).
// A: [v][z<128][y:256][x:256] complex fp32 = 134 MB total.
// B (packed): [v][z<128][y:256][x<128] complex fp32 = 67 MB total.
static constexpr size_t VS   = 8388608;  // 128*256*256 per volume (A)
static constexpr int    ZSTR = 65536;    // 256*256
static constexpr int    YSTR = 256;
static constexpr size_t VSB  = 4194304;  // 128*256*128 per volume (B)
static constexpr int    BZS  = 32768;    // 256*128
static constexpr int    BYS  = 128;
static constexpr int    LSTR = 261;      // LDS line stride (float2); 261 mod 16 = 5 spreads bank pairs

__device__ __forceinline__ float2 cmulf(float2 a, float2 b){
    return make_float2(a.x*b.x - a.y*b.y, a.x*b.y + a.y*b.x);
}

constexpr int BREV(int k){ return ((k&1)<<3)|((k&2)<<1)|((k&4)>>1)|((k&8)>>3); }

__device__ __forceinline__ void bf(float2& a, float2& b, float c, float s){
    float tx = a.x - b.x, ty = a.y - b.y;
    a.x += b.x; a.y += b.y;
    b.x = tx*c - ty*s;
    b.y = tx*s + ty*c;
}

// Fully-unrolled 16-pt DIF FFT, natural input, bit-reversed output: X[k] = r[BREV(k)].
// DIR=-1 forward (e^{-i...}), DIR=+1 inverse (unscaled).
template<int DIR>
__device__ __forceinline__ void fft16(float2 r[16]){
    constexpr float D = (float)DIR;
    constexpr float C16[8] = {1.f, 0.92387953f, 0.70710678f, 0.38268343f, 0.f, -0.38268343f, -0.70710678f, -0.92387953f};
    constexpr float S16[8] = {0.f, 0.38268343f, 0.70710678f, 0.92387953f, 1.f, 0.92387953f, 0.70710678f, 0.38268343f};
#pragma unroll
    for (int j = 0; j < 8; ++j) bf(r[j], r[j+8], C16[j], D*S16[j]);
    constexpr float C8[4] = {1.f, 0.70710678f, 0.f, -0.70710678f};
    constexpr float S8[4] = {0.f, 0.70710678f, 1.f, 0.70710678f};
#pragma unroll
    for (int g = 0; g < 16; g += 8)
#pragma unroll
        for (int j = 0; j < 4; ++j) bf(r[g+j], r[g+j+4], C8[j], D*S8[j]);
#pragma unroll
    for (int g = 0; g < 16; g += 4){
        bf(r[g],   r[g+2], 1.f, 0.f);
        bf(r[g+1], r[g+3], 0.f, D);
    }
#pragma unroll
    for (int g = 0; g < 16; g += 2) bf(r[g], r[g+1], 1.f, 0.f);
}

// Middle of four-step 256-pt FFT (256 = 16x16). On entry r[n1] = x[16*n1 + t]
// for this thread's n2=t, line l. On exit r[BREV(k2)] = X[t + 16*k2].
template<int DIR>
__device__ __forceinline__ void mid256(float2 r[16], float2* sh, int t, int l){
    fft16<DIR>(r);
    float s, c;
    __sincosf((float)DIR * 0.0245436926f * (float)t, &s, &c);  // w1 = e^{DIR*2pi*i*t/256}
    float2 w1 = make_float2(c, s), wc = w1;
#pragma unroll
    for (int k1 = 1; k1 < 16; ++k1){
        float2& v = r[BREV(k1)];
        v = cmulf(v, wc);
        wc = cmulf(wc, w1);
    }
    __syncthreads();
#pragma unroll
    for (int k1 = 0; k1 < 16; ++k1)
        sh[l*LSTR + k1*16 + ((t + k1) & 15)] = r[BREV(k1)];
    __syncthreads();
#pragma unroll
    for (int n2 = 0; n2 < 16; ++n2)
        r[n2] = sh[l*LSTR + t*16 + ((n2 + t) & 15)];
    fft16<DIR>(r);
}

// Strided-axis FFT: 16 consecutive x per block (128-B segments), stride S elements.
// Reads only idx<NIN (rest structurally zero), writes only idx<NOUT.
template<int DIR, int NIN, int NOUT>
__device__ __forceinline__ void fft_strided(float2* g, int S){
    __shared__ float2 sh[16*LSTR];
    int t = threadIdx.x >> 4, l = threadIdx.x & 15;
    float2 r[16];
#pragma unroll
    for (int n1 = 0; n1 < 16; ++n1)
        r[n1] = (n1 < NIN/16) ? g[(size_t)(16*n1 + t)*S + l] : make_float2(0.f, 0.f);
    mid256<DIR>(r, sh, t, l);
#pragma unroll
    for (int k2 = 0; k2 < 16; ++k2)
        if (k2 < NOUT/16) g[(size_t)(t + 16*k2)*S + l] = r[BREV(k2)];
}

// P1: read input, val = sqrt(relu(f*gz^2)), zero-pad 128->256, forward FFT along x.
__global__ void __launch_bounds__(256) k_p1(const float* __restrict__ in, float2* __restrict__ A){
    __shared__ float2 sh[16*LSTR];
    __shared__ float shin[16*130];
    int th = threadIdx.x, bid = blockIdx.x;          // v*1024 + z*8 + yc
    int yc = bid & 7, z = (bid >> 3) & 127, v = bid >> 10;
    float gz = z * (1.0f/127.0f);
    float g2 = gz*gz;
    const float* src = in + (((size_t)(v*128 + z))*128 + yc*16)*128;
    for (int idx = th; idx < 2048; idx += 256){
        float val = src[idx] * g2;
        shin[(idx >> 7)*130 + (idx & 127)] = val > 0.f ? sqrtf(val) : 0.f;
    }
    __syncthreads();
    int t = th >> 4, l = th & 15;
    float2 r[16];
#pragma unroll
    for (int n1 = 0; n1 < 16; ++n1)
        r[n1] = (n1 < 8) ? make_float2(shin[l*130 + 16*n1 + t], 0.f) : make_float2(0.f, 0.f);
    mid256<-1>(r, sh, t, l);
    __syncthreads();
#pragma unroll
    for (int k2 = 0; k2 < 16; ++k2) sh[l*LSTR + t + 16*k2] = r[BREV(k2)];
    __syncthreads();
    float2* dst = A + (size_t)v*VS + (size_t)z*ZSTR + (size_t)(yc*16)*YSTR;
    for (int idx = th; idx < 4096; idx += 256)
        dst[idx] = sh[(idx >> 8)*LSTR + (idx & 255)];
}

// P2: forward FFT along y for z<128, all x. Read y<128, write all 256. In-place.
__global__ void __launch_bounds__(256) k_p2(float2* __restrict__ A){
    int bid = blockIdx.x;                            // v*2048 + z*16 + xb
    int xb = bid & 15, z = (bid >> 4) & 127, v = bid >> 11;
    fft_strided<-1,128,256>(A + (size_t)v*VS + (size_t)z*ZSTR + xb*16, YSTR);
}

// P3: forward FFT along z for all (y,x). Read z<128, write only z<128. In-place.
__global__ void __launch_bounds__(256) k_p3(float2* __restrict__ A){
    int bid = blockIdx.x;                            // v*4096 + y*16 + xb
    int xb = bid & 15, y = (bid >> 4) & 255, v = bid >> 12;
    fft_strided<-1,128,128>(A + (size_t)v*VS + (size_t)y*YSTR + xb*16, ZSTR);
}

// P45: fused Stolt resample (natural coords, branchless) + x-iFFT.
// Block = (v, zn, 16-row y tile). Gathers from A, FFTs, stores packed B x<128.
__global__ void __launch_bounds__(256) k_p45(const float2* __restrict__ A, float2* __restrict__ B){
    __shared__ float2 sh[16*LSTR];
    int tid = threadIdx.x, bid = blockIdx.x;         // v*2048 + zn*16 + yc
    int yc = bid & 15, zn = (bid >> 4) & 127, v = bid >> 11;
    const float2* Av = A + (size_t)v*VS;
    int xn = tid;
    int xs = (xn + 128) & 255;
    float gx = (xs - 128) * (1.0f/128.0f);
    float gz = zn * (1.0f/128.0f);
    float b2 = 0.1024f*gx*gx + gz*gz;
    unsigned cm = (unsigned)((xn - 1) & 255), cn = (unsigned)xn;
    float wxm = (xn == 128) ? 0.f : 1.f;
#pragma unroll 4
    for (int l = 0; l < 16; ++l){
        int yn = yc*16 + l;
        int ys = (yn + 128) & 255;
        float gy = (ys - 128) * (1.0f/128.0f);
        float gznew = sqrtf(b2 + 0.1024f*gy*gy);
        float pz = gznew*128.0f + 127.5f;
        float z0f = floorf(pz);
        float dz = pz - z0f;
        int zp0 = (int)z0f - 128;
        float w0 = ((unsigned)zp0 < 128u) ? (1.0f - dz) : 0.f;
        float w1 = ((unsigned)(zp0 + 1) < 128u) ? dz : 0.f;
        unsigned b0 = (unsigned)(zp0 & 127) * ZSTR;
        unsigned b1 = (unsigned)((zp0 + 1) & 127) * ZSTR;
        unsigned rm = (unsigned)((yn - 1) & 255) * YSTR;
        unsigned rn = (unsigned)yn * YSTR;
        float wym = (yn == 128) ? 0.f : 1.f;
        float2 p0a = Av[b0+rm+cm], p0b = Av[b0+rm+cn], p0c = Av[b0+rn+cm], p0d = Av[b0+rn+cn];
        float2 p1a = Av[b1+rm+cm], p1b = Av[b1+rm+cn], p1c = Av[b1+rn+cm], p1d = Av[b1+rn+cn];
        float s0x = wym*(wxm*p0a.x + p0b.x) + (wxm*p0c.x + p0d.x);
        float s0y = wym*(wxm*p0a.y + p0b.y) + (wxm*p0c.y + p0d.y);
        float s1x = wym*(wxm*p1a.x + p1b.x) + (wxm*p1c.x + p1d.x);
        float s1y = wym*(wxm*p1a.y + p1b.y) + (wxm*p1c.y + p1d.y);
        float wf = 0.25f * gz / (gznew + 1e-8f);     // 0.25 = wy*wx; zn==0 mask via gz=0
        sh[l*LSTR + xn] = make_float2((w0*s0x + w1*s1x)*wf, (w0*s0y + w1*s1y)*wf);
    }
    __syncthreads();
    int t = tid >> 4, ll = tid & 15;
    float2 r[16];
#pragma unroll
    for (int n1 = 0; n1 < 16; ++n1) r[n1] = sh[ll*LSTR + 16*n1 + t];
    mid256<1>(r, sh, t, ll);                         // internal syncthreads protects sh reuse
    __syncthreads();
#pragma unroll
    for (int k2 = 0; k2 < 8; ++k2) sh[ll*LSTR + t + 16*k2] = r[BREV(k2)];  // x<128 only
    __syncthreads();
    float2* dst = B + (size_t)v*VSB + (size_t)zn*BZS + (size_t)(yc*16)*BYS;
    for (int idx = tid; idx < 2048; idx += 256)
        dst[idx] = sh[(idx >> 7)*LSTR + (idx & 127)];
}

// P6: inverse FFT along y on packed B (x<128). Read all 256 y, write y<128. In-place.
__global__ void __launch_bounds__(256) k_p6(float2* __restrict__ B){
    int bid = blockIdx.x;                            // v*1024 + zn*8 + xb
    int xb = bid & 7, zn = (bid >> 3) & 127, v = bid >> 10;
    fft_strided<1,256,128>(B + (size_t)v*VSB + (size_t)zn*BZS + xb*16, BYS);
}

// P7: inverse FFT along z for y<128, x<128 on packed B. Read zn<128,
// output real part of z<128 scaled by 1/256^3 into d_out.
__global__ void __launch_bounds__(256) k_p7(const float2* __restrict__ B, float* __restrict__ out){
    __shared__ float2 sh[16*LSTR];
    int bid = blockIdx.x;                            // v*1024 + y*8 + xb
    int xb = bid & 7, y = (bid >> 3) & 127, v = bid >> 10;
    const float2* g = B + (size_t)v*VSB + (size_t)y*BYS + xb*16;
    int t = threadIdx.x >> 4, l = threadIdx.x & 15;
    float2 r[16];
#pragma unroll
    for (int n1 = 0; n1 < 16; ++n1)
        r[n1] = (n1 < 8) ? g[(size_t)(16*n1 + t)*BZS + l] : make_float2(0.f, 0.f);
    mid256<1>(r, sh, t, l);
    const float sc = 1.0f/16777216.0f;               // 1/256^3
    float* dst = out + ((size_t)(v*128)*128 + y)*128 + xb*16 + l;
#pragma unroll
    for (int k2 = 0; k2 < 8; ++k2)                   // k = t + 16*k2 < 128
        dst[(size_t)(t + 16*k2)*16384] = r[BREV(k2)].x * sc;
}

extern "C" void kernel_launch(void* const* d_in, const int* in_sizes, int n_in,
                              void* d_out, int out_size, void* d_ws, size_t ws_size,
                              hipStream_t stream){
    const float* in = (const float*)d_in[0];
    float* out = (float*)d_out;
    float2* A = (float2*)d_ws;             // 134 MB
    float2* B = A + 2*VS;                  // 67 MB packed
    k_p1 <<< 2048, 256, 0, stream>>>(in, A);
    k_p2 <<< 4096, 256, 0, stream>>>(A);
    k_p3 <<< 8192, 256, 0, stream>>>(A);
    k_p45<<< 4096, 256, 0, stream>>>(A, B);
    k_p6 <<< 2048, 256, 0, stream>>>(B);
    k_p7 <<< 2048, 256, 0, stream>>>(B, out);
}

// Round 4
// 236.350 us; speedup vs baseline: 2.0614x; 1.3261x over previous
//
#include <hip/hip_runtime.h>

// Geometry: M=N=128, padded S=256. Two volumes (b*d=2).
// A: [v][z<128][y:256][x:256] complex fp32 = 134 MB total.
// B (packed): [v][z<128][y:256][x<128] complex fp32 = 67 MB total.
static constexpr size_t VS   = 8388608;  // 128*256*256 per volume (A)
static constexpr int    ZSTR = 65536;    // 256*256
static constexpr int    YSTR = 256;
static constexpr size_t VSB  = 4194304;  // 128*256*128 per volume (B)
static constexpr int    BZS  = 32768;    // 256*128
static constexpr int    BYS  = 128;
static constexpr int    LSTR = 261;      // LDS line stride (float2); odd stride spreads bank pairs

__device__ __forceinline__ float2 cmulf(float2 a, float2 b){
    return make_float2(a.x*b.x - a.y*b.y, a.x*b.y + a.y*b.x);
}

constexpr int BREV(int k){ return ((k&1)<<3)|((k&2)<<1)|((k&4)>>1)|((k&8)>>3); }

__device__ __forceinline__ void bf(float2& a, float2& b, float c, float s){
    float tx = a.x - b.x, ty = a.y - b.y;
    a.x += b.x; a.y += b.y;
    b.x = tx*c - ty*s;
    b.y = tx*s + ty*c;
}

// Fully-unrolled 16-pt DIF FFT, natural input, bit-reversed output: X[k] = r[BREV(k)].
// DIR=-1 forward, DIR=+1 inverse (unscaled).
template<int DIR>
__device__ __forceinline__ void fft16(float2 r[16]){
    constexpr float D = (float)DIR;
    constexpr float C16[8] = {1.f, 0.92387953f, 0.70710678f, 0.38268343f, 0.f, -0.38268343f, -0.70710678f, -0.92387953f};
    constexpr float S16[8] = {0.f, 0.38268343f, 0.70710678f, 0.92387953f, 1.f, 0.92387953f, 0.70710678f, 0.38268343f};
#pragma unroll
    for (int j = 0; j < 8; ++j) bf(r[j], r[j+8], C16[j], D*S16[j]);
    constexpr float C8[4] = {1.f, 0.70710678f, 0.f, -0.70710678f};
    constexpr float S8[4] = {0.f, 0.70710678f, 1.f, 0.70710678f};
#pragma unroll
    for (int g = 0; g < 16; g += 8)
#pragma unroll
        for (int j = 0; j < 4; ++j) bf(r[g+j], r[g+j+4], C8[j], D*S8[j]);
#pragma unroll
    for (int g = 0; g < 16; g += 4){
        bf(r[g],   r[g+2], 1.f, 0.f);
        bf(r[g+1], r[g+3], 0.f, D);
    }
#pragma unroll
    for (int g = 0; g < 16; g += 2) bf(r[g], r[g+1], 1.f, 0.f);
}

// Middle of four-step 256-pt FFT (256 = 16x16). On entry r[n1] = x[16*n1 + t]
// for this thread's n2=t, line l. On exit r[BREV(k2)] = X[t + 16*k2].
template<int DIR>
__device__ __forceinline__ void mid256(float2 r[16], float2* sh, int t, int l){
    fft16<DIR>(r);
    float s, c;
    __sincosf((float)DIR * 0.0245436926f * (float)t, &s, &c);
    float2 w1 = make_float2(c, s), wc = w1;
#pragma unroll
    for (int k1 = 1; k1 < 16; ++k1){
        float2& v = r[BREV(k1)];
        v = cmulf(v, wc);
        wc = cmulf(wc, w1);
    }
    __syncthreads();
#pragma unroll
    for (int k1 = 0; k1 < 16; ++k1)
        sh[l*LSTR + k1*16 + ((t + k1) & 15)] = r[BREV(k1)];
    __syncthreads();
#pragma unroll
    for (int n2 = 0; n2 < 16; ++n2)
        r[n2] = sh[l*LSTR + t*16 + ((n2 + t) & 15)];
    fft16<DIR>(r);
}

// Strided-axis FFT: 16 consecutive x per block, stride S elements.
// Reads only idx<NIN (rest structurally zero), writes only idx<NOUT.
template<int DIR, int NIN, int NOUT>
__device__ __forceinline__ void fft_strided(float2* g, int S){
    __shared__ float2 sh[16*LSTR];
    int t = threadIdx.x >> 4, l = threadIdx.x & 15;
    float2 r[16];
#pragma unroll
    for (int n1 = 0; n1 < 16; ++n1)
        r[n1] = (n1 < NIN/16) ? g[(size_t)(16*n1 + t)*S + l] : make_float2(0.f, 0.f);
    mid256<DIR>(r, sh, t, l);
#pragma unroll
    for (int k2 = 0; k2 < 16; ++k2)
        if (k2 < NOUT/16) g[(size_t)(t + 16*k2)*S + l] = r[BREV(k2)];
}

// P1: read input, val = sqrt(relu(f*gz^2)), zero-pad 128->256, forward FFT along x,
// then apply the exact half-pixel x-average in the epilogue:
//   avg[k] = 0.5*(X[k] + X[(k-1)&255]), with the prev tap DROPPED at k=128
//   (shifted xs=0 boundary; k=0 wraps cyclically to 255).
__global__ void __launch_bounds__(256) k_p1(const float* __restrict__ in, float2* __restrict__ A){
    __shared__ float2 sh[16*LSTR];
    __shared__ float shin[16*130];
    int th = threadIdx.x, bid = blockIdx.x;          // v*1024 + z*8 + yc
    int yc = bid & 7, z = (bid >> 3) & 127, v = bid >> 10;
    float gz = z * (1.0f/127.0f);
    float g2 = gz*gz;
    const float* src = in + (((size_t)(v*128 + z))*128 + yc*16)*128;
    for (int idx = th; idx < 2048; idx += 256){
        float val = src[idx] * g2;
        shin[(idx >> 7)*130 + (idx & 127)] = val > 0.f ? sqrtf(val) : 0.f;
    }
    __syncthreads();
    int t = th >> 4, l = th & 15;
    float2 r[16];
#pragma unroll
    for (int n1 = 0; n1 < 16; ++n1)
        r[n1] = (n1 < 8) ? make_float2(shin[l*130 + 16*n1 + t], 0.f) : make_float2(0.f, 0.f);
    mid256<-1>(r, sh, t, l);
    __syncthreads();
#pragma unroll
    for (int k2 = 0; k2 < 16; ++k2) sh[l*LSTR + t + 16*k2] = r[BREV(k2)];
    __syncthreads();
    float2* dst = A + (size_t)v*VS + (size_t)z*ZSTR + (size_t)(yc*16)*YSTR;
    for (int idx = th; idx < 4096; idx += 256){
        int line = idx >> 8, k = idx & 255;
        float2 a = sh[line*LSTR + k];
        float2 p = sh[line*LSTR + ((k - 1) & 255)];
        if (k == 128) p = make_float2(0.f, 0.f);
        dst[idx] = make_float2(0.5f*(a.x + p.x), 0.5f*(a.y + p.y));
    }
}

// P2: forward FFT along y for z<128, all x (read y<128, write 256), then apply
// the exact half-pixel y-average in the epilogue (same rule as P1's x-average).
__global__ void __launch_bounds__(256) k_p2(float2* __restrict__ A){
    __shared__ float2 sh[16*LSTR];
    int bid = blockIdx.x;                            // v*2048 + z*16 + xb
    int xb = bid & 15, z = (bid >> 4) & 127, v = bid >> 11;
    float2* g = A + (size_t)v*VS + (size_t)z*ZSTR + xb*16;
    int t = threadIdx.x >> 4, l = threadIdx.x & 15;
    float2 r[16];
#pragma unroll
    for (int n1 = 0; n1 < 16; ++n1)
        r[n1] = (n1 < 8) ? g[(size_t)(16*n1 + t)*YSTR + l] : make_float2(0.f, 0.f);
    mid256<-1>(r, sh, t, l);
    __syncthreads();
#pragma unroll
    for (int k2 = 0; k2 < 16; ++k2) sh[l*LSTR + t + 16*k2] = r[BREV(k2)];
    __syncthreads();
#pragma unroll
    for (int k2 = 0; k2 < 16; ++k2){
        int k = t + 16*k2;
        float2 a = sh[l*LSTR + k];
        float2 p = sh[l*LSTR + ((k - 1) & 255)];
        if (k == 128) p = make_float2(0.f, 0.f);
        g[(size_t)k*YSTR + l] = make_float2(0.5f*(a.x + p.x), 0.5f*(a.y + p.y));
    }
}

// P3: forward FFT along z for all (y,x). Read z<128, write only z<128. In-place.
__global__ void __launch_bounds__(256) k_p3(float2* __restrict__ A){
    int bid = blockIdx.x;                            // v*4096 + y*16 + xb
    int xb = bid & 15, y = (bid >> 4) & 255, v = bid >> 12;
    fft_strided<-1,128,128>(A + (size_t)v*VS + (size_t)y*YSTR + xb*16, ZSTR);
}

// P45: fused Stolt z-resample (2 taps — x/y averaging already baked into A) + x-iFFT.
// Block = (v, zn, 16-row y tile). Gathers from A, FFTs, stores packed B x<128.
__global__ void __launch_bounds__(256) k_p45(const float2* __restrict__ A, float2* __restrict__ B){
    __shared__ float2 sh[16*LSTR];
    int tid = threadIdx.x, bid = blockIdx.x;         // v*2048 + zn*16 + yc
    int yc = bid & 15, zn = (bid >> 4) & 127, v = bid >> 11;
    const float2* Av = A + (size_t)v*VS;
    int xn = tid;
    float gx = (xn < 128 ? xn : xn - 256) * (1.0f/128.0f);
    float gz = zn * (1.0f/128.0f);
    float b2 = 0.1024f*gx*gx + gz*gz;
#pragma unroll 8
    for (int l = 0; l < 16; ++l){
        int yn = yc*16 + l;
        float gy = (yn < 128 ? yn : yn - 256) * (1.0f/128.0f);
        float gznew = sqrtf(b2 + 0.1024f*gy*gy);
        float pz = gznew*128.0f + 127.5f;            // shifted-z coord - 128 offset folded below
        float z0f = floorf(pz);
        float dz = pz - z0f;
        int zp0 = (int)z0f - 128;                    // natural z of first tap, >= 0
        float wf = gz * __builtin_amdgcn_rcpf(gznew + 1e-8f);  // |gz|/gznew; zn==0 mask via gz=0
        float w0 = (((unsigned)zp0     < 128u) ? (1.0f - dz) : 0.f) * wf;
        float w1 = (((unsigned)(zp0+1) < 128u) ? dz : 0.f) * wf;
        unsigned col = (unsigned)yn*YSTR + (unsigned)xn;
        float2 v0 = Av[(size_t)((unsigned)(zp0 & 127) * ZSTR) + col];
        float2 v1 = Av[(size_t)((unsigned)((zp0 + 1) & 127) * ZSTR) + col];
        sh[l*LSTR + xn] = make_float2(w0*v0.x + w1*v1.x, w0*v0.y + w1*v1.y);
    }
    __syncthreads();
    int t = tid >> 4, ll = tid & 15;
    float2 r[16];
#pragma unroll
    for (int n1 = 0; n1 < 16; ++n1) r[n1] = sh[ll*LSTR + 16*n1 + t];
    mid256<1>(r, sh, t, ll);
    __syncthreads();
#pragma unroll
    for (int k2 = 0; k2 < 8; ++k2) sh[ll*LSTR + t + 16*k2] = r[BREV(k2)];  // x<128 only
    __syncthreads();
    float2* dst = B + (size_t)v*VSB + (size_t)zn*BZS + (size_t)(yc*16)*BYS;
    for (int idx = tid; idx < 2048; idx += 256)
        dst[idx] = sh[(idx >> 7)*LSTR + (idx & 127)];
}

// P6: inverse FFT along y on packed B (x<128). Read all 256 y, write y<128. In-place.
__global__ void __launch_bounds__(256) k_p6(float2* __restrict__ B){
    int bid = blockIdx.x;                            // v*1024 + zn*8 + xb
    int xb = bid & 7, zn = (bid >> 3) & 127, v = bid >> 10;
    fft_strided<1,256,128>(B + (size_t)v*VSB + (size_t)zn*BZS + xb*16, BYS);
}

// P7: inverse FFT along z for y<128, x<128 on packed B. Read zn<128,
// output real part of z<128 scaled by 1/256^3 into d_out.
__global__ void __launch_bounds__(256) k_p7(const float2* __restrict__ B, float* __restrict__ out){
    __shared__ float2 sh[16*LSTR];
    int bid = blockIdx.x;                            // v*1024 + y*8 + xb
    int xb = bid & 7, y = (bid >> 3) & 127, v = bid >> 10;
    const float2* g = B + (size_t)v*VSB + (size_t)y*BYS + xb*16;
    int t = threadIdx.x >> 4, l = threadIdx.x & 15;
    float2 r[16];
#pragma unroll
    for (int n1 = 0; n1 < 16; ++n1)
        r[n1] = (n1 < 8) ? g[(size_t)(16*n1 + t)*BZS + l] : make_float2(0.f, 0.f);
    mid256<1>(r, sh, t, l);
    const float sc = 1.0f/16777216.0f;               // 1/256^3
    float* dst = out + ((size_t)(v*128)*128 + y)*128 + xb*16 + l;
#pragma unroll
    for (int k2 = 0; k2 < 8; ++k2)                   // k = t + 16*k2 < 128
        dst[(size_t)(t + 16*k2)*16384] = r[BREV(k2)].x * sc;
}

extern "C" void kernel_launch(void* const* d_in, const int* in_sizes, int n_in,
                              void* d_out, int out_size, void* d_ws, size_t ws_size,
                              hipStream_t stream){
    const float* in = (const float*)d_in[0];
    float* out = (float*)d_out;
    float2* A = (float2*)d_ws;             // 134 MB
    float2* B = A + 2*VS;                  // 67 MB packed
    k_p1 <<< 2048, 256, 0, stream>>>(in, A);
    k_p2 <<< 4096, 256, 0, stream>>>(A);
    k_p3 <<< 8192, 256, 0, stream>>>(A);
    k_p45<<< 4096, 256, 0, stream>>>(A, B);
    k_p6 <<< 2048, 256, 0, stream>>>(B);
    k_p7 <<< 2048, 256, 0, stream>>>(B, out);
}

// Round 5
// 227.270 us; speedup vs baseline: 2.1438x; 1.0400x over previous
//
#include <hip/hip_runtime.h>

// Geometry: M=N=128, padded S=256. Two volumes (b*d=2).
// A: [v][z<128][y:256][x:256] complex fp32 = 134 MB total.
// B (packed): [v][z<128][y:256][x<128] complex fp32 = 67 MB total.
static constexpr size_t VS   = 8388608;  // 128*256*256 per volume (A)
static constexpr int    ZSTR = 65536;    // 256*256
static constexpr int    YSTR = 256;
static constexpr size_t VSB  = 4194304;  // 128*256*128 per volume (B)
static constexpr int    BZS  = 32768;    // 256*128
static constexpr int    BYS  = 128;
static constexpr int    LSTR = 261;      // LDS line stride (vf2); odd stride spreads bank pairs

typedef float vf2 __attribute__((ext_vector_type(2)));  // complex: .x=re, .y=im -> v_pk_* f32

__device__ __forceinline__ vf2 cmul(vf2 a, vf2 b){
    vf2 asw; asw.x = -a.y; asw.y = a.x;       // i*a
    return a*b.x + asw*b.y;                   // pk_mul + pk_fma
}

constexpr int BREV(int k){ return ((k&1)<<3)|((k&2)<<1)|((k&4)>>1)|((k&8)>>3); }

// Butterfly: a' = a+b; b' = (a-b) rotated by (c,s). Packed: 4-5 VOP3P ops.
__device__ __forceinline__ void bf(vf2& a, vf2& b, float c, float s){
    vf2 sum = a + b;
    vf2 dif = a - b;
    vf2 dsw; dsw.x = -dif.y; dsw.y = dif.x;   // i*dif
    b = dif*c + dsw*s;                        // (tx*c - ty*s, ty*c + tx*s)
    a = sum;
}

// Fully-unrolled 16-pt DIF FFT, natural input, bit-reversed output: X[k] = r[BREV(k)].
// DIR=-1 forward, DIR=+1 inverse (unscaled).
template<int DIR>
__device__ __forceinline__ void fft16(vf2 r[16]){
    constexpr float D = (float)DIR;
    constexpr float C16[8] = {1.f, 0.92387953f, 0.70710678f, 0.38268343f, 0.f, -0.38268343f, -0.70710678f, -0.92387953f};
    constexpr float S16[8] = {0.f, 0.38268343f, 0.70710678f, 0.92387953f, 1.f, 0.92387953f, 0.70710678f, 0.38268343f};
#pragma unroll
    for (int j = 0; j < 8; ++j) bf(r[j], r[j+8], C16[j], D*S16[j]);
    constexpr float C8[4] = {1.f, 0.70710678f, 0.f, -0.70710678f};
    constexpr float S8[4] = {0.f, 0.70710678f, 1.f, 0.70710678f};
#pragma unroll
    for (int g = 0; g < 16; g += 8)
#pragma unroll
        for (int j = 0; j < 4; ++j) bf(r[g+j], r[g+j+4], C8[j], D*S8[j]);
#pragma unroll
    for (int g = 0; g < 16; g += 4){
        bf(r[g],   r[g+2], 1.f, 0.f);
        bf(r[g+1], r[g+3], 0.f, D);
    }
#pragma unroll
    for (int g = 0; g < 16; g += 2) bf(r[g], r[g+1], 1.f, 0.f);
}

// Middle of four-step 256-pt FFT (256 = 16x16). On entry r[n1] = x[16*n1 + t]
// for this thread's n2=t, line l. On exit r[BREV(k2)] = X[t + 16*k2].
template<int DIR>
__device__ __forceinline__ void mid256(vf2 r[16], vf2* sh, int t, int l){
    fft16<DIR>(r);
    float s, c;
    __sincosf((float)DIR * 0.0245436926f * (float)t, &s, &c);
    vf2 w1; w1.x = c; w1.y = s;
    vf2 wc = w1;
#pragma unroll
    for (int k1 = 1; k1 < 16; ++k1){
        vf2& v = r[BREV(k1)];
        v = cmul(v, wc);
        wc = cmul(wc, w1);
    }
    __syncthreads();
#pragma unroll
    for (int k1 = 0; k1 < 16; ++k1)
        sh[l*LSTR + k1*16 + ((t + k1) & 15)] = r[BREV(k1)];
    __syncthreads();
#pragma unroll
    for (int n2 = 0; n2 < 16; ++n2)
        r[n2] = sh[l*LSTR + t*16 + ((n2 + t) & 15)];
    fft16<DIR>(r);
}

// Strided-axis FFT: 16 consecutive x per block, stride S elements.
// Reads only idx<NIN (rest structurally zero), writes only idx<NOUT.
template<int DIR, int NIN, int NOUT>
__device__ __forceinline__ void fft_strided(vf2* g, int S){
    __shared__ vf2 sh[16*LSTR];
    int t = threadIdx.x >> 4, l = threadIdx.x & 15;
    vf2 r[16];
    vf2 zero; zero.x = 0.f; zero.y = 0.f;
#pragma unroll
    for (int n1 = 0; n1 < 16; ++n1)
        r[n1] = (n1 < NIN/16) ? g[(size_t)(16*n1 + t)*S + l] : zero;
    mid256<DIR>(r, sh, t, l);
#pragma unroll
    for (int k2 = 0; k2 < 16; ++k2)
        if (k2 < NOUT/16) g[(size_t)(t + 16*k2)*S + l] = r[BREV(k2)];
}

// P1: read input, val = sqrt(relu(f*gz^2)), zero-pad 128->256, forward FFT along x,
// then apply the exact half-pixel x-average in the epilogue:
//   avg[k] = 0.5*(X[k] + X[(k-1)&255]), prev tap DROPPED at k=128.
__global__ void __launch_bounds__(256) k_p1(const float* __restrict__ in, vf2* __restrict__ A){
    __shared__ vf2 sh[16*LSTR];
    __shared__ float shin[16*130];
    int th = threadIdx.x, bid = blockIdx.x;          // v*1024 + z*8 + yc
    int yc = bid & 7, z = (bid >> 3) & 127, v = bid >> 10;
    float gz = z * (1.0f/127.0f);
    float g2 = gz*gz;
    const float* src = in + (((size_t)(v*128 + z))*128 + yc*16)*128;
    for (int idx = th; idx < 2048; idx += 256){
        float val = src[idx] * g2;
        shin[(idx >> 7)*130 + (idx & 127)] = val > 0.f ? sqrtf(val) : 0.f;
    }
    __syncthreads();
    int t = th >> 4, l = th & 15;
    vf2 r[16];
    vf2 zero; zero.x = 0.f; zero.y = 0.f;
#pragma unroll
    for (int n1 = 0; n1 < 16; ++n1){
        r[n1] = zero;
        if (n1 < 8) r[n1].x = shin[l*130 + 16*n1 + t];
    }
    mid256<-1>(r, sh, t, l);
    __syncthreads();
#pragma unroll
    for (int k2 = 0; k2 < 16; ++k2) sh[l*LSTR + t + 16*k2] = r[BREV(k2)];
    __syncthreads();
    vf2* dst = A + (size_t)v*VS + (size_t)z*ZSTR + (size_t)(yc*16)*YSTR;
    for (int idx = th; idx < 4096; idx += 256){
        int line = idx >> 8, k = idx & 255;
        vf2 a = sh[line*LSTR + k];
        vf2 p = sh[line*LSTR + ((k - 1) & 255)];
        if (k == 128) p = zero;
        dst[idx] = (a + p)*0.5f;
    }
}

// P2: forward FFT along y for z<128, all x (read y<128, write 256), then apply
// the exact half-pixel y-average in the epilogue (same rule as P1's x-average).
__global__ void __launch_bounds__(256) k_p2(vf2* __restrict__ A){
    __shared__ vf2 sh[16*LSTR];
    int bid = blockIdx.x;                            // v*2048 + z*16 + xb
    int xb = bid & 15, z = (bid >> 4) & 127, v = bid >> 11;
    vf2* g = A + (size_t)v*VS + (size_t)z*ZSTR + xb*16;
    int t = threadIdx.x >> 4, l = threadIdx.x & 15;
    vf2 r[16];
    vf2 zero; zero.x = 0.f; zero.y = 0.f;
#pragma unroll
    for (int n1 = 0; n1 < 16; ++n1)
        r[n1] = (n1 < 8) ? g[(size_t)(16*n1 + t)*YSTR + l] : zero;
    mid256<-1>(r, sh, t, l);
    __syncthreads();
#pragma unroll
    for (int k2 = 0; k2 < 16; ++k2) sh[l*LSTR + t + 16*k2] = r[BREV(k2)];
    __syncthreads();
#pragma unroll
    for (int k2 = 0; k2 < 16; ++k2){
        int k = t + 16*k2;
        vf2 a = sh[l*LSTR + k];
        vf2 p = sh[l*LSTR + ((k - 1) & 255)];
        if (k == 128) p = zero;
        g[(size_t)k*YSTR + l] = (a + p)*0.5f;
    }
}

// P3: forward FFT along z for all (y,x). Read z<128, write only z<128. In-place.
__global__ void __launch_bounds__(256) k_p3(vf2* __restrict__ A){
    int bid = blockIdx.x;                            // v*4096 + y*16 + xb
    int xb = bid & 15, y = (bid >> 4) & 255, v = bid >> 12;
    fft_strided<-1,128,128>(A + (size_t)v*VS + (size_t)y*YSTR + xb*16, ZSTR);
}

// P45: fused Stolt z-resample (2 taps — x/y averaging already baked into A) + x-iFFT.
// Block = (v, zn, 16-row y tile). Gathers from A, FFTs, stores packed B x<128.
__global__ void __launch_bounds__(256) k_p45(const vf2* __restrict__ A, vf2* __restrict__ B){
    __shared__ vf2 sh[16*LSTR];
    int tid = threadIdx.x, bid = blockIdx.x;         // v*2048 + zn*16 + yc
    int yc = bid & 15, zn = (bid >> 4) & 127, v = bid >> 11;
    const vf2* Av = A + (size_t)v*VS;
    int xn = tid;
    float gx = (xn < 128 ? xn : xn - 256) * (1.0f/128.0f);
    float gz = zn * (1.0f/128.0f);
    float b2 = 0.1024f*gx*gx + gz*gz;
#pragma unroll 8
    for (int l = 0; l < 16; ++l){
        int yn = yc*16 + l;
        float gy = (yn < 128 ? yn : yn - 256) * (1.0f/128.0f);
        float gznew = sqrtf(b2 + 0.1024f*gy*gy);
        float pz = gznew*128.0f + 127.5f;
        float z0f = floorf(pz);
        float dz = pz - z0f;
        int zp0 = (int)z0f - 128;                    // natural z of first tap
        float wf = gz * __builtin_amdgcn_rcpf(gznew + 1e-8f);  // |gz|/gznew; zn==0 -> 0
        float w0 = (((unsigned)zp0     < 128u) ? (1.0f - dz) : 0.f) * wf;
        float w1 = (((unsigned)(zp0+1) < 128u) ? dz : 0.f) * wf;
        unsigned col = (unsigned)yn*YSTR + (unsigned)xn;
        vf2 v0 = Av[(size_t)((unsigned)(zp0 & 127) * ZSTR) + col];
        vf2 v1 = Av[(size_t)((unsigned)((zp0 + 1) & 127) * ZSTR) + col];
        sh[l*LSTR + xn] = v0*w0 + v1*w1;             // pk_mul + pk_fma
    }
    __syncthreads();
    int t = tid >> 4, ll = tid & 15;
    vf2 r[16];
#pragma unroll
    for (int n1 = 0; n1 < 16; ++n1) r[n1] = sh[ll*LSTR + 16*n1 + t];
    mid256<1>(r, sh, t, ll);
    __syncthreads();
#pragma unroll
    for (int k2 = 0; k2 < 8; ++k2) sh[ll*LSTR + t + 16*k2] = r[BREV(k2)];  // x<128 only
    __syncthreads();
    vf2* dst = B + (size_t)v*VSB + (size_t)zn*BZS + (size_t)(yc*16)*BYS;
    for (int idx = tid; idx < 2048; idx += 256)
        dst[idx] = sh[(idx >> 7)*LSTR + (idx & 127)];
}

// P6: inverse FFT along y on packed B (x<128). Read all 256 y, write y<128. In-place.
__global__ void __launch_bounds__(256) k_p6(vf2* __restrict__ B){
    int bid = blockIdx.x;                            // v*1024 + zn*8 + xb
    int xb = bid & 7, zn = (bid >> 3) & 127, v = bid >> 10;
    fft_strided<1,256,128>(B + (size_t)v*VSB + (size_t)zn*BZS + xb*16, BYS);
}

// P7: inverse FFT along z for y<128, x<128 on packed B. Read zn<128,
// output real part of z<128 scaled by 1/256^3 into d_out.
__global__ void __launch_bounds__(256) k_p7(const vf2* __restrict__ B, float* __restrict__ out){
    __shared__ vf2 sh[16*LSTR];
    int bid = blockIdx.x;                            // v*1024 + y*8 + xb
    int xb = bid & 7, y = (bid >> 3) & 127, v = bid >> 10;
    const vf2* g = B + (size_t)v*VSB + (size_t)y*BYS + xb*16;
    int t = threadIdx.x >> 4, l = threadIdx.x & 15;
    vf2 r[16];
    vf2 zero; zero.x = 0.f; zero.y = 0.f;
#pragma unroll
    for (int n1 = 0; n1 < 16; ++n1)
        r[n1] = (n1 < 8) ? g[(size_t)(16*n1 + t)*BZS + l] : zero;
    mid256<1>(r, sh, t, l);
    const float sc = 1.0f/16777216.0f;               // 1/256^3
    float* dst = out + ((size_t)(v*128)*128 + y)*128 + xb*16 + l;
#pragma unroll
    for (int k2 = 0; k2 < 8; ++k2)                   // k = t + 16*k2 < 128
        dst[(size_t)(t + 16*k2)*16384] = r[BREV(k2)].x * sc;
}

extern "C" void kernel_launch(void* const* d_in, const int* in_sizes, int n_in,
                              void* d_out, int out_size, void* d_ws, size_t ws_size,
                              hipStream_t stream){
    const float* in = (const float*)d_in[0];
    float* out = (float*)d_out;
    vf2* A = (vf2*)d_ws;                   // 134 MB
    vf2* B = A + 2*VS;                     // 67 MB packed
    k_p1 <<< 2048, 256, 0, stream>>>(in, A);
    k_p2 <<< 4096, 256, 0, stream>>>(A);
    k_p3 <<< 8192, 256, 0, stream>>>(A);
    k_p45<<< 4096, 256, 0, stream>>>(A, B);
    k_p6 <<< 2048, 256, 0, stream>>>(B);
    k_p7 <<< 2048, 256, 0, stream>>>(B, out);
}

// Round 6
// 219.198 us; speedup vs baseline: 2.2227x; 1.0368x over previous
//
#include <hip/hip_runtime.h>

// Geometry: M=N=128, padded S=256. Two volumes (b*d=2).
// A: [v][z<128][y:256][x:256] complex fp32 = 134 MB total.
// B (packed): [v][z<128][y:256][x<128] complex fp32 = 67 MB total.
static constexpr size_t VS   = 8388608;  // 128*256*256 per volume (A)
static constexpr int    ZSTR = 65536;    // 256*256
static constexpr int    YSTR = 256;
static constexpr size_t VSB  = 4194304;  // 128*256*128 per volume (B)
static constexpr int    BZS  = 32768;    // 256*128
static constexpr int    BYS  = 128;
static constexpr int    LSTR = 261;      // LDS line stride (vf2); odd stride spreads bank pairs

typedef float vf2 __attribute__((ext_vector_type(2)));  // complex: .x=re, .y=im -> v_pk_* f32

__device__ __forceinline__ vf2 cmul(vf2 a, vf2 b){
    vf2 asw; asw.x = -a.y; asw.y = a.x;       // i*a
    return a*b.x + asw*b.y;                   // pk_mul + pk_fma
}

constexpr int BREV(int k){ return ((k&1)<<3)|((k&2)<<1)|((k&4)>>1)|((k&8)>>3); }

// Butterfly: a' = a+b; b' = (a-b) rotated by (c,s). Packed VOP3P.
__device__ __forceinline__ void bf(vf2& a, vf2& b, float c, float s){
    vf2 sum = a + b;
    vf2 dif = a - b;
    vf2 dsw; dsw.x = -dif.y; dsw.y = dif.x;   // i*dif
    b = dif*c + dsw*s;
    a = sum;
}

// Fully-unrolled 16-pt DIF FFT, natural input, bit-reversed output: X[k] = r[BREV(k)].
// DIR=-1 forward, DIR=+1 inverse (unscaled). Trivial rotations constant-fold.
template<int DIR>
__device__ __forceinline__ void fft16(vf2 r[16]){
    constexpr float D = (float)DIR;
    constexpr float C16[8] = {1.f, 0.92387953f, 0.70710678f, 0.38268343f, 0.f, -0.38268343f, -0.70710678f, -0.92387953f};
    constexpr float S16[8] = {0.f, 0.38268343f, 0.70710678f, 0.92387953f, 1.f, 0.92387953f, 0.70710678f, 0.38268343f};
#pragma unroll
    for (int j = 0; j < 8; ++j) bf(r[j], r[j+8], C16[j], D*S16[j]);
    constexpr float C8[4] = {1.f, 0.70710678f, 0.f, -0.70710678f};
    constexpr float S8[4] = {0.f, 0.70710678f, 1.f, 0.70710678f};
#pragma unroll
    for (int g = 0; g < 16; g += 8)
#pragma unroll
        for (int j = 0; j < 4; ++j) bf(r[g+j], r[g+j+4], C8[j], D*S8[j]);
#pragma unroll
    for (int g = 0; g < 16; g += 4){
        bf(r[g],   r[g+2], 1.f, 0.f);
        bf(r[g+1], r[g+3], 0.f, D);
    }
#pragma unroll
    for (int g = 0; g < 16; g += 2) bf(r[g], r[g+1], 1.f, 0.f);
}

// Per-block twiddle table: tw[a*16+b] = e^{DIR*2pi*i*a*b/256} (symmetric in a,b).
// 256 threads -> one sincos each. Caller must barrier before first use.
__device__ __forceinline__ void init_tw(vf2* tw, float dir){
    int tid = threadIdx.x;
    float ang = dir * 0.0245436926f * (float)((tid >> 4)*(tid & 15));
    float s, c; __sincosf(ang, &s, &c);
    vf2 w; w.x = c; w.y = s;
    tw[tid] = w;
}

// Middle of four-step 256-pt FFT (256 = 16x16). On entry r[n1] = x[16*n1 + t]
// for this thread's n2=t, line l. On exit r[BREV(k2)] = X[t + 16*k2].
// tw: LDS table (DIR baked in by init_tw). XOR-swizzled conflict-free transpose.
template<int DIR>
__device__ __forceinline__ void mid256(vf2 r[16], vf2* sh, const vf2* tw, int t, int l){
    fft16<DIR>(r);
#pragma unroll
    for (int k1 = 1; k1 < 16; ++k1)
        r[BREV(k1)] = cmul(r[BREV(k1)], tw[k1*16 + t]);   // broadcast read across l
    __syncthreads();
#pragma unroll
    for (int k1 = 0; k1 < 16; ++k1)
        sh[l*LSTR + k1*16 + (t ^ k1)] = r[BREV(k1)];
    __syncthreads();
#pragma unroll
    for (int n2 = 0; n2 < 16; ++n2)
        r[n2] = sh[l*LSTR + t*16 + (n2 ^ t)];
    fft16<DIR>(r);
}

// Strided-axis FFT: 16 consecutive x per block, stride S elements.
// Reads only idx<NIN (rest structurally zero), writes only idx<NOUT.
template<int DIR, int NIN, int NOUT>
__device__ __forceinline__ void fft_strided(vf2* g, int S){
    __shared__ vf2 sh[16*LSTR];
    __shared__ vf2 tw[256];
    init_tw(tw, (float)DIR);
    __syncthreads();                                 // tw ready (cheap: only LDS writes pending)
    int t = threadIdx.x >> 4, l = threadIdx.x & 15;
    vf2 r[16];
    vf2 zero; zero.x = 0.f; zero.y = 0.f;
#pragma unroll
    for (int n1 = 0; n1 < 16; ++n1)
        r[n1] = (n1 < NIN/16) ? g[(size_t)(16*n1 + t)*S + l] : zero;
    mid256<DIR>(r, sh, tw, t, l);
#pragma unroll
    for (int k2 = 0; k2 < 16; ++k2)
        if (k2 < NOUT/16) g[(size_t)(t + 16*k2)*S + l] = r[BREV(k2)];
}

// P1: read input, val = sqrt(relu(f*gz^2)), zero-pad 128->256, forward FFT along x,
// then the exact half-pixel x-average epilogue:
//   avg[k] = 0.5*(X[k] + X[(k-1)&255]), prev tap DROPPED at k=128.
__global__ void __launch_bounds__(256) k_p1(const float* __restrict__ in, vf2* __restrict__ A){
    __shared__ vf2 sh[16*LSTR];
    __shared__ vf2 tw[256];
    __shared__ float shin[16*130];
    init_tw(tw, -1.f);
    int th = threadIdx.x, bid = blockIdx.x;          // v*1024 + z*8 + yc
    int yc = bid & 7, z = (bid >> 3) & 127, v = bid >> 10;
    float gz = z * (1.0f/127.0f);
    float g2 = gz*gz;
    const float* src = in + (((size_t)(v*128 + z))*128 + yc*16)*128;
    for (int idx = th; idx < 2048; idx += 256){
        float val = src[idx] * g2;
        shin[(idx >> 7)*130 + (idx & 127)] = val > 0.f ? sqrtf(val) : 0.f;
    }
    __syncthreads();
    int t = th >> 4, l = th & 15;
    vf2 r[16];
    vf2 zero; zero.x = 0.f; zero.y = 0.f;
#pragma unroll
    for (int n1 = 0; n1 < 16; ++n1){
        r[n1] = zero;
        if (n1 < 8) r[n1].x = shin[l*130 + 16*n1 + t];
    }
    mid256<-1>(r, sh, tw, t, l);
    __syncthreads();
#pragma unroll
    for (int k2 = 0; k2 < 16; ++k2) sh[l*LSTR + t + 16*k2] = r[BREV(k2)];
    __syncthreads();
    vf2* dst = A + (size_t)v*VS + (size_t)z*ZSTR + (size_t)(yc*16)*YSTR;
    for (int idx = th; idx < 4096; idx += 256){
        int line = idx >> 8, k = idx & 255;
        vf2 a = sh[line*LSTR + k];
        vf2 p = sh[line*LSTR + ((k - 1) & 255)];
        if (k == 128) p = zero;
        dst[idx] = (a + p)*0.5f;
    }
}

// P2: forward FFT along y for z<128, all x (read y<128, write 256), then the
// exact half-pixel y-average epilogue (same rule as P1's x-average).
__global__ void __launch_bounds__(256) k_p2(vf2* __restrict__ A){
    __shared__ vf2 sh[16*LSTR];
    __shared__ vf2 tw[256];
    init_tw(tw, -1.f);
    __syncthreads();
    int bid = blockIdx.x;                            // v*2048 + z*16 + xb
    int xb = bid & 15, z = (bid >> 4) & 127, v = bid >> 11;
    vf2* g = A + (size_t)v*VS + (size_t)z*ZSTR + xb*16;
    int t = threadIdx.x >> 4, l = threadIdx.x & 15;
    vf2 r[16];
    vf2 zero; zero.x = 0.f; zero.y = 0.f;
#pragma unroll
    for (int n1 = 0; n1 < 16; ++n1)
        r[n1] = (n1 < 8) ? g[(size_t)(16*n1 + t)*YSTR + l] : zero;
    mid256<-1>(r, sh, tw, t, l);
    __syncthreads();
#pragma unroll
    for (int k2 = 0; k2 < 16; ++k2) sh[l*LSTR + t + 16*k2] = r[BREV(k2)];
    __syncthreads();
#pragma unroll
    for (int k2 = 0; k2 < 16; ++k2){
        int k = t + 16*k2;
        vf2 a = sh[l*LSTR + k];
        vf2 p = sh[l*LSTR + ((k - 1) & 255)];
        if (k == 128) p = zero;
        g[(size_t)k*YSTR + l] = (a + p)*0.5f;
    }
}

// P3: forward FFT along z for all (y,x). Read z<128, write only z<128. In-place.
__global__ void __launch_bounds__(256) k_p3(vf2* __restrict__ A){
    int bid = blockIdx.x;                            // v*4096 + y*16 + xb
    int xb = bid & 15, y = (bid >> 4) & 255, v = bid >> 12;
    fft_strided<-1,128,128>(A + (size_t)v*VS + (size_t)y*YSTR + xb*16, ZSTR);
}

// P45: fused Stolt z-resample (2 taps — x/y averaging baked into A) + x-iFFT.
// Block = (v, zn, 16-row y tile). Gathers from A, FFTs, stores packed B x<128.
__global__ void __launch_bounds__(256) k_p45(const vf2* __restrict__ A, vf2* __restrict__ B){
    __shared__ vf2 sh[16*LSTR];
    __shared__ vf2 tw[256];
    init_tw(tw, 1.f);
    int tid = threadIdx.x, bid = blockIdx.x;         // v*2048 + zn*16 + yc
    int yc = bid & 15, zn = (bid >> 4) & 127, v = bid >> 11;
    const vf2* Av = A + (size_t)v*VS;
    int xn = tid;
    float gx = (xn < 128 ? xn : xn - 256) * (1.0f/128.0f);
    float gz = zn * (1.0f/128.0f);
    float b2 = 0.1024f*gx*gx + gz*gz;
#pragma unroll 8
    for (int l = 0; l < 16; ++l){
        int yn = yc*16 + l;
        float gy = (yn < 128 ? yn : yn - 256) * (1.0f/128.0f);
        float s2 = b2 + 0.1024f*gy*gy;
        float rs = __builtin_amdgcn_rsqf(s2 + 1e-12f);   // 1/gznew (guard: zn==0 row -> wf=0 exactly)
        float gznew = s2 * rs;                           // sqrt(s2)
        float pz = gznew*128.0f + 127.5f;
        int zi = (int)pz;                                // trunc == floor (pz > 0)
        float dz = pz - (float)zi;
        int zp0 = zi - 128;                              // natural z of first tap
        float wf = gz * rs;                              // gz/gznew
        float w0 = (((unsigned)zp0     < 128u) ? (1.0f - dz) : 0.f) * wf;
        float w1 = (((unsigned)(zp0+1) < 128u) ? dz : 0.f) * wf;
        unsigned col = (unsigned)yn*YSTR + (unsigned)xn;
        vf2 v0 = Av[(size_t)((unsigned)(zp0 & 127) * ZSTR) + col];
        vf2 v1 = Av[(size_t)((unsigned)((zp0 + 1) & 127) * ZSTR) + col];
        sh[l*LSTR + xn] = v0*w0 + v1*w1;                 // pk_mul + pk_fma
    }
    __syncthreads();                                     // also covers tw init
    int t = tid >> 4, ll = tid & 15;
    vf2 r[16];
#pragma unroll
    for (int n1 = 0; n1 < 16; ++n1) r[n1] = sh[ll*LSTR + 16*n1 + t];
    mid256<1>(r, sh, tw, t, ll);
    __syncthreads();
#pragma unroll
    for (int k2 = 0; k2 < 8; ++k2) sh[ll*LSTR + t + 16*k2] = r[BREV(k2)];  // x<128 only
    __syncthreads();
    vf2* dst = B + (size_t)v*VSB + (size_t)zn*BZS + (size_t)(yc*16)*BYS;
    for (int idx = tid; idx < 2048; idx += 256)
        dst[idx] = sh[(idx >> 7)*LSTR + (idx & 127)];
}

// P6: inverse FFT along y on packed B (x<128). Read all 256 y, write y<128. In-place.
__global__ void __launch_bounds__(256) k_p6(vf2* __restrict__ B){
    int bid = blockIdx.x;                            // v*1024 + zn*8 + xb
    int xb = bid & 7, zn = (bid >> 3) & 127, v = bid >> 10;
    fft_strided<1,256,128>(B + (size_t)v*VSB + (size_t)zn*BZS + xb*16, BYS);
}

// P7: inverse FFT along z for y<128, x<128 on packed B. Read zn<128,
// output real part of z<128 scaled by 1/256^3 into d_out.
__global__ void __launch_bounds__(256) k_p7(const vf2* __restrict__ B, float* __restrict__ out){
    __shared__ vf2 sh[16*LSTR];
    __shared__ vf2 tw[256];
    init_tw(tw, 1.f);
    __syncthreads();
    int bid = blockIdx.x;                            // v*1024 + y*8 + xb
    int xb = bid & 7, y = (bid >> 3) & 127, v = bid >> 10;
    const vf2* g = B + (size_t)v*VSB + (size_t)y*BYS + xb*16;
    int t = threadIdx.x >> 4, l = threadIdx.x & 15;
    vf2 r[16];
    vf2 zero; zero.x = 0.f; zero.y = 0.f;
#pragma unroll
    for (int n1 = 0; n1 < 16; ++n1)
        r[n1] = (n1 < 8) ? g[(size_t)(16*n1 + t)*BZS + l] : zero;
    mid256<1>(r, sh, tw, t, l);
    const float sc = 1.0f/16777216.0f;               // 1/256^3
    float* dst = out + ((size_t)(v*128)*128 + y)*128 + xb*16 + l;
#pragma unroll
    for (int k2 = 0; k2 < 8; ++k2)                   // k = t + 16*k2 < 128
        dst[(size_t)(t + 16*k2)*16384] = r[BREV(k2)].x * sc;
}

extern "C" void kernel_launch(void* const* d_in, const int* in_sizes, int n_in,
                              void* d_out, int out_size, void* d_ws, size_t ws_size,
                              hipStream_t stream){
    const float* in = (const float*)d_in[0];
    float* out = (float*)d_out;
    vf2* A = (vf2*)d_ws;                   // 134 MB
    vf2* B = A + 2*VS;                     // 67 MB packed
    k_p1 <<< 2048, 256, 0, stream>>>(in, A);
    k_p2 <<< 4096, 256, 0, stream>>>(A);
    k_p3 <<< 8192, 256, 0, stream>>>(A);
    k_p45<<< 4096, 256, 0, stream>>>(A, B);
    k_p6 <<< 2048, 256, 0, stream>>>(B);
    k_p7 <<< 2048, 256, 0, stream>>>(B, out);
}